// Round 1
// baseline (883.803 us; speedup 1.0000x reference)
//
#include <hip/hip_runtime.h>
#include <hip/hip_bf16.h>

// Llama attention block: B=2, S=2048, H=4096, NH=32, NKV=8, HD=128, GQA 4:1.
// Pipeline (all bf16 MFMA, fp32 accumulate):
//   1. convert hidden + Wq/Wk/Wv (concat) + Wo to bf16
//   2. QKV = X @ Wqkv^T        (M=4096, N=6144, K=4096)  128^2-tile MFMA GEMM
//   3. RoPE + scatter to [B,NH,S,HD] / [B,NKV,S,HD]; fold 1/sqrt(128) into Q
//   4. flash attention (causal), 64 q-rows/block, KV tiles of 64
//   5. out = AttnOut @ Wo^T    (fp32 out)

typedef __bf16 bf16;
typedef __bf16 bf16x8 __attribute__((ext_vector_type(8)));
typedef float f32x4 __attribute__((ext_vector_type(4)));

__device__ __forceinline__ void async16(const bf16* g, bf16* l) {
  __builtin_amdgcn_global_load_lds(
      (const __attribute__((address_space(1))) void*)g,
      (__attribute__((address_space(3))) void*)l,
      16, 0, 0);
}

// ---------------- fp32 -> bf16 convert (8 elem/thread) ----------------
__global__ void k_cvt(const float* __restrict__ s, bf16* __restrict__ d, int n8) {
  int i = blockIdx.x * 256 + threadIdx.x;
  if (i >= n8) return;
  const float4* sp = (const float4*)s + (size_t)i * 2;
  float4 a = sp[0], b = sp[1];
  bf16x8 o = { (bf16)a.x, (bf16)a.y, (bf16)a.z, (bf16)a.w,
               (bf16)b.x, (bf16)b.y, (bf16)b.z, (bf16)b.w };
  *(bf16x8*)(d + (size_t)i * 8) = o;
}

// ---------------- GEMM: C[M,N] = A[M,K] * Bw[N,K]^T (both K-contiguous) ----
// 128x128 tile, BK=32, 4 waves (2x2 of 64x64), 16x16x32 bf16 MFMA.
// global_load_lds staging with 2-bit XOR swizzle (rule 21: pre-swizzled src).
template <typename OutT>
__global__ __launch_bounds__(256) void k_gemm_bt(
    const bf16* __restrict__ A, const bf16* __restrict__ Bw,
    OutT* __restrict__ C, int M, int N, int K) {
  __shared__ __align__(16) bf16 As[128 * 32];
  __shared__ __align__(16) bf16 Bs[128 * 32];
  const int tid = threadIdx.x;
  const int lane = tid & 63;
  const int w = tid >> 6;
  const int wm = w >> 1, wn = w & 1;
  const int l16 = lane & 15, lh = lane >> 4;
  const size_t m0 = (size_t)blockIdx.y * 128, n0 = (size_t)blockIdx.x * 128;

  f32x4 acc[4][4] = {};

  // staging chunks: 512 x 16B per tile; thread does 2 for A, 2 for B.
  // chunk c: row=c>>2, swizzled slot = (c&3)^(row&3)
  const int c0 = (w * 2) * 64 + lane;
  const int r0 = c0 >> 2;
  const int s0 = ((c0 & 3) ^ (r0 & 3)) * 8;
  const int c1 = c0 + 64;
  const int r1 = c1 >> 2;
  const int s1 = ((c1 & 3) ^ (r1 & 3)) * 8;
  const bf16* Ag0 = A + (m0 + r0) * K + s0;
  const bf16* Ag1 = A + (m0 + r1) * K + s1;
  const bf16* Bg0 = Bw + (n0 + r0) * K + s0;
  const bf16* Bg1 = Bw + (n0 + r1) * K + s1;
  bf16* As0 = As + (w * 2 + 0) * 512;
  bf16* As1 = As + (w * 2 + 1) * 512;
  bf16* Bs0 = Bs + (w * 2 + 0) * 512;
  bf16* Bs1 = Bs + (w * 2 + 1) * 512;

  for (int k0 = 0; k0 < K; k0 += 32) {
    async16(Ag0 + k0, As0);
    async16(Ag1 + k0, As1);
    async16(Bg0 + k0, Bs0);
    async16(Bg1 + k0, Bs1);
    __syncthreads();
    bf16x8 af[4], bg[4];
#pragma unroll
    for (int mi = 0; mi < 4; ++mi) {
      int row = wm * 64 + mi * 16 + l16;
      int byte = (row * 64 + lh * 16) ^ ((row & 3) << 4);
      af[mi] = *(const bf16x8*)((const char*)As + byte);
    }
#pragma unroll
    for (int ni = 0; ni < 4; ++ni) {
      int row = wn * 64 + ni * 16 + l16;
      int byte = (row * 64 + lh * 16) ^ ((row & 3) << 4);
      bg[ni] = *(const bf16x8*)((const char*)Bs + byte);
    }
#pragma unroll
    for (int mi = 0; mi < 4; ++mi)
#pragma unroll
      for (int ni = 0; ni < 4; ++ni)
        acc[mi][ni] = __builtin_amdgcn_mfma_f32_16x16x32_bf16(af[mi], bg[ni], acc[mi][ni], 0, 0, 0);
    __syncthreads();
  }

  // C/D layout (m89): col = lane&15, row = (lane>>4)*4 + reg
#pragma unroll
  for (int mi = 0; mi < 4; ++mi) {
    size_t row = m0 + wm * 64 + mi * 16 + lh * 4;
#pragma unroll
    for (int ni = 0; ni < 4; ++ni) {
      size_t col = n0 + wn * 64 + ni * 16 + l16;
#pragma unroll
      for (int j = 0; j < 4; ++j)
        C[(row + j) * N + col] = (OutT)acc[mi][ni][j];
    }
  }
}

// ---------------- RoPE + scatter ----------------
// QKV rows: token-major [4096][6144]. slots: 0..31 Q, 32..39 K, 40..47 V.
// thread = (token, slot, pair p in 0..63); handles (p, p+64).
__global__ void k_rope(const bf16* __restrict__ QKV, bf16* __restrict__ Qr,
                       bf16* __restrict__ Kr, bf16* __restrict__ Vr) {
  int gid = blockIdx.x * 256 + threadIdx.x;
  int p = gid & 63;
  int rest = gid >> 6;
  int slot = rest % 48;
  int tok = rest / 48;
  int s = tok & 2047;
  int b = tok >> 11;
  const bf16* src = QKV + (size_t)tok * 6144 + slot * 128;
  float x1 = (float)src[p], x2 = (float)src[p + 64];
  bf16* dst;
  float o1, o2;
  if (slot < 40) {
    // inv_freq[p] = 10000^(-p/64); log2(10000)=13.287712379549449
    float f = exp2f((float)p * (-13.287712379549449f / 64.0f));
    float ang = (float)s * f;
    float sn, cn;
    sincosf(ang, &sn, &cn);
    o1 = x1 * cn - x2 * sn;
    o2 = x2 * cn + x1 * sn;
    if (slot < 32) {
      o1 *= 0.08838834764831845f;  // fold 1/sqrt(128) into Q
      o2 *= 0.08838834764831845f;
      dst = Qr + (((size_t)b * 32 + slot) * 2048 + s) * 128;
    } else {
      dst = Kr + (((size_t)b * 8 + (slot - 32)) * 2048 + s) * 128;
    }
  } else {
    o1 = x1;
    o2 = x2;
    dst = Vr + (((size_t)b * 8 + (slot - 40)) * 2048 + s) * 128;
  }
  dst[p] = (bf16)o1;
  dst[p + 64] = (bf16)o2;
}

// ---------------- flash attention (causal, GQA 4:1) ----------------
// block = (b, h, q-block of 64). 4 waves; wave w owns q rows [w*16, w*16+16).
// K tile [64][128] in LDS, XOR-swizzled (G4 fix); V transposed [128][72] padded;
// per-wave P [16][72] for the C-layout -> A-layout transpose.
__global__ __launch_bounds__(256) void k_flash(
    const bf16* __restrict__ Qr, const bf16* __restrict__ Kr,
    const bf16* __restrict__ Vr, bf16* __restrict__ Out) {
  __shared__ __align__(16) bf16 Kt[64 * 128];
  __shared__ __align__(16) bf16 Vt[128 * 72];
  __shared__ __align__(16) bf16 Pl[4][16 * 72];
  const int tid = threadIdx.x;
  const int lane = tid & 63;
  const int w = tid >> 6;
  const int l16 = lane & 15, lh = lane >> 4;
  const int qb = blockIdx.x & 31;
  const int h = (blockIdx.x >> 5) & 31;
  const int b = blockIdx.x >> 10;
  const int hkv = h >> 2;
  const int q0 = qb * 64;

  // Q fragments in registers (A-operand layout): row=l16, k=(lh*8+j)
  bf16x8 qf[4];
  {
    const bf16* qbase =
        Qr + (((size_t)(b * 32 + h)) * 2048 + q0 + w * 16 + l16) * 128 + lh * 8;
#pragma unroll
    for (int kc = 0; kc < 4; ++kc) qf[kc] = *(const bf16x8*)(qbase + kc * 32);
  }

  f32x4 acc[8] = {};
  float mrow[4] = {-1e30f, -1e30f, -1e30f, -1e30f};
  float lrow[4] = {0.f, 0.f, 0.f, 0.f};

  const bf16* Kbase = Kr + ((size_t)(b * 8 + hkv)) * 2048 * 128;
  const bf16* Vbase = Vr + ((size_t)(b * 8 + hkv)) * 2048 * 128;
  bf16* P = &Pl[w][0];

  for (int kt = 0; kt <= qb; ++kt) {
    // K stage: 1024 x 16B chunks via global_load_lds, swizzled source
    {
      const int cb = (w * 4) * 64 + lane;
#pragma unroll
      for (int i = 0; i < 4; ++i) {
        int c = cb + i * 64;
        int row = c >> 4;
        int cs = ((c & 15) ^ (row & 7)) * 8;
        async16(Kbase + ((size_t)(kt * 64 + row)) * 128 + cs, Kt + (w * 4 + i) * 512);
      }
    }
    // V stage transposed: coalesced 2B global reads, b128 LDS writes
#pragma unroll
    for (int i = 0; i < 4; ++i) {
      int c = i * 256 + tid;
      int d = c & 127;
      int k0 = (c >> 7) * 8;
      bf16x8 vv;
#pragma unroll
      for (int j = 0; j < 8; ++j)
        vv[j] = Vbase[((size_t)(kt * 64 + k0 + j)) * 128 + d];
      *(bf16x8*)&Vt[d * 72 + k0] = vv;
    }
    __syncthreads();

    // S = Q K^T  (D row = q local, D col = key local)
    f32x4 sf[4];
#pragma unroll
    for (int ni = 0; ni < 4; ++ni) {
      f32x4 a = {0.f, 0.f, 0.f, 0.f};
      int row = ni * 16 + l16;
#pragma unroll
      for (int kc = 0; kc < 4; ++kc) {
        int byte = (row * 256 + kc * 64 + lh * 16) ^ ((row & 7) << 4);
        bf16x8 kf = *(const bf16x8*)((const char*)Kt + byte);
        a = __builtin_amdgcn_mfma_f32_16x16x32_bf16(qf[kc], kf, a, 0, 0, 0);
      }
      sf[ni] = a;
    }
    if (kt == qb) {
#pragma unroll
      for (int ni = 0; ni < 4; ++ni) {
        int kl = ni * 16 + l16;
#pragma unroll
        for (int j = 0; j < 4; ++j) {
          int ql = w * 16 + lh * 4 + j;
          if (kl > ql) sf[ni][j] = -1e30f;
        }
      }
    }
    // online softmax (rows shared across the 16-lane group)
    float corr[4];
#pragma unroll
    for (int j = 0; j < 4; ++j) {
      float mx = fmaxf(fmaxf(sf[0][j], sf[1][j]), fmaxf(sf[2][j], sf[3][j]));
      mx = fmaxf(mx, __shfl_xor(mx, 1));
      mx = fmaxf(mx, __shfl_xor(mx, 2));
      mx = fmaxf(mx, __shfl_xor(mx, 4));
      mx = fmaxf(mx, __shfl_xor(mx, 8));
      float mnew = fmaxf(mrow[j], mx);
      corr[j] = __expf(mrow[j] - mnew);
      float rs = 0.f;
#pragma unroll
      for (int ni = 0; ni < 4; ++ni) {
        float pv = __expf(sf[ni][j] - mnew);
        sf[ni][j] = pv;
        rs += pv;
      }
      rs += __shfl_xor(rs, 1);
      rs += __shfl_xor(rs, 2);
      rs += __shfl_xor(rs, 4);
      rs += __shfl_xor(rs, 8);
      lrow[j] = lrow[j] * corr[j] + rs;
      mrow[j] = mnew;
    }
#pragma unroll
    for (int di = 0; di < 8; ++di)
#pragma unroll
      for (int j = 0; j < 4; ++j) acc[di][j] *= corr[j];
    // P -> LDS (per-wave region; wave-internal LDS ops are in-order)
#pragma unroll
    for (int ni = 0; ni < 4; ++ni)
#pragma unroll
      for (int j = 0; j < 4; ++j)
        P[(lh * 4 + j) * 72 + ni * 16 + l16] = (bf16)sf[ni][j];
    // O += P @ V
#pragma unroll
    for (int kc = 0; kc < 2; ++kc) {
      bf16x8 pa = *(const bf16x8*)(P + l16 * 72 + kc * 32 + lh * 8);
#pragma unroll
      for (int di = 0; di < 8; ++di) {
        bf16x8 vb = *(const bf16x8*)(&Vt[(di * 16 + l16) * 72 + kc * 32 + lh * 8]);
        acc[di] = __builtin_amdgcn_mfma_f32_16x16x32_bf16(pa, vb, acc[di], 0, 0, 0);
      }
    }
    __syncthreads();
  }

  float inv[4];
#pragma unroll
  for (int j = 0; j < 4; ++j) inv[j] = 1.0f / lrow[j];
  bf16* obase =
      Out + ((size_t)b * 2048 + q0 + w * 16 + lh * 4) * 4096 + h * 128 + l16;
#pragma unroll
  for (int j = 0; j < 4; ++j)
#pragma unroll
    for (int di = 0; di < 8; ++di)
      obase[(size_t)j * 4096 + di * 16] = (bf16)(acc[di][j] * inv[j]);
}

// ---------------- launch ----------------
extern "C" void kernel_launch(void* const* d_in, const int* in_sizes, int n_in,
                              void* d_out, int out_size, void* d_ws, size_t ws_size,
                              hipStream_t stream) {
  const float* hidden = (const float*)d_in[0];
  // d_in[1] = attention_mask (causal by construction, implemented directly)
  // d_in[2] = position_ids  (arange, implemented directly)
  const float* Wq = (const float*)d_in[3];
  const float* Wk = (const float*)d_in[4];
  const float* Wv = (const float*)d_in[5];
  const float* Wo = (const float*)d_in[6];
  float* out = (float*)d_out;

  // workspace layout (bytes):
  //   A: Xb [4096*4096] bf16 @ 0          (later reused as AttnOut)
  //   B: Wqkv [6144*4096] bf16 @ 32M      (later reused as Wo_bf16)
  //   C: QKV [4096*6144] bf16 @ 80M
  //   D: Qr  [2,32,2048,128] bf16 @ 128M
  //   E: Kr  [2,8,2048,128] bf16 @ 160M
  //   F: Vr  [2,8,2048,128] bf16 @ 168M     total = 176 MiB
  char* ws = (char*)d_ws;
  if (ws_size < 184549376u) return;  // fail visibly rather than corrupt
  bf16* Xb = (bf16*)(ws);
  bf16* Wqkv = (bf16*)(ws + 33554432u);
  bf16* QKV = (bf16*)(ws + 83886080u);
  bf16* Qr = (bf16*)(ws + 134217728u);
  bf16* Kr = (bf16*)(ws + 167772160u);
  bf16* Vr = (bf16*)(ws + 176160768u);
  bf16* AttnO = Xb;   // Xb dead after QKV GEMM
  bf16* Wob = Wqkv;   // Wqkv dead after QKV GEMM

  k_cvt<<<8192, 256, 0, stream>>>(hidden, Xb, 2097152);
  k_cvt<<<8192, 256, 0, stream>>>(Wq, Wqkv, 2097152);
  k_cvt<<<2048, 256, 0, stream>>>(Wk, Wqkv + 16777216u, 524288);
  k_cvt<<<2048, 256, 0, stream>>>(Wv, Wqkv + 20971520u, 524288);
  k_gemm_bt<bf16><<<dim3(48, 32), 256, 0, stream>>>(Xb, Wqkv, QKV, 4096, 6144, 4096);
  k_rope<<<49152, 256, 0, stream>>>(QKV, Qr, Kr, Vr);
  k_cvt<<<8192, 256, 0, stream>>>(Wo, Wob, 2097152);
  k_flash<<<2048, 256, 0, stream>>>(Qr, Kr, Vr, AttnO);
  k_gemm_bt<float><<<dim3(32, 32), 256, 0, stream>>>(AttnO, Wob, out, 4096, 4096, 4096);
}

// Round 2
// 722.610 us; speedup vs baseline: 1.2231x; 1.2231x over previous
//
#include <hip/hip_runtime.h>
#include <hip/hip_bf16.h>

// Llama attention block: B=2, S=2048, H=4096, NH=32, NKV=8, HD=128, GQA 4:1.
// Pipeline (bf16 MFMA, fp32 accumulate):
//   1. convert hidden + Wq/Wk/Wv (concat) + Wo to bf16
//   2. QKV = X @ Wqkv^T        (M=4096, N=6144, K=4096)  128^2-tile MFMA GEMM
//   3. RoPE (Q,K only) + scatter; fold 1/sqrt(128) into Q
//   4. V transpose kernel: QKV -> Vtg [b][hkv][128 d][2048 s]
//   5. flash attention (causal): QBLK=128, KV tile 64, dbuf LDS, paired blocks
//   6. out = AttnOut @ Wo^T    (fp32 out)

typedef __bf16 bf16;
typedef __bf16 bf16x8 __attribute__((ext_vector_type(8)));
typedef float f32x4 __attribute__((ext_vector_type(4)));

__device__ __forceinline__ void async16(const bf16* g, bf16* l) {
  __builtin_amdgcn_global_load_lds(
      (const __attribute__((address_space(1))) void*)g,
      (__attribute__((address_space(3))) void*)l,
      16, 0, 0);
}

// ---------------- fp32 -> bf16 convert (8 elem/thread) ----------------
__global__ void k_cvt(const float* __restrict__ s, bf16* __restrict__ d, int n8) {
  int i = blockIdx.x * 256 + threadIdx.x;
  if (i >= n8) return;
  const float4* sp = (const float4*)s + (size_t)i * 2;
  float4 a = sp[0], b = sp[1];
  bf16x8 o = { (bf16)a.x, (bf16)a.y, (bf16)a.z, (bf16)a.w,
               (bf16)b.x, (bf16)b.y, (bf16)b.z, (bf16)b.w };
  *(bf16x8*)(d + (size_t)i * 8) = o;
}

// ---------------- GEMM: C[M,N] = A[M,K] * Bw[N,K]^T ----------------
template <typename OutT>
__global__ __launch_bounds__(256) void k_gemm_bt(
    const bf16* __restrict__ A, const bf16* __restrict__ Bw,
    OutT* __restrict__ C, int M, int N, int K) {
  __shared__ __align__(16) bf16 As[128 * 32];
  __shared__ __align__(16) bf16 Bs[128 * 32];
  const int tid = threadIdx.x;
  const int lane = tid & 63;
  const int w = tid >> 6;
  const int wm = w >> 1, wn = w & 1;
  const int l16 = lane & 15, lh = lane >> 4;
  const size_t m0 = (size_t)blockIdx.y * 128, n0 = (size_t)blockIdx.x * 128;

  f32x4 acc[4][4] = {};

  const int c0 = (w * 2) * 64 + lane;
  const int r0 = c0 >> 2;
  const int s0 = ((c0 & 3) ^ (r0 & 3)) * 8;
  const int c1 = c0 + 64;
  const int r1 = c1 >> 2;
  const int s1 = ((c1 & 3) ^ (r1 & 3)) * 8;
  const bf16* Ag0 = A + (m0 + r0) * K + s0;
  const bf16* Ag1 = A + (m0 + r1) * K + s1;
  const bf16* Bg0 = Bw + (n0 + r0) * K + s0;
  const bf16* Bg1 = Bw + (n0 + r1) * K + s1;
  bf16* As0 = As + (w * 2 + 0) * 512;
  bf16* As1 = As + (w * 2 + 1) * 512;
  bf16* Bs0 = Bs + (w * 2 + 0) * 512;
  bf16* Bs1 = Bs + (w * 2 + 1) * 512;

  for (int k0 = 0; k0 < K; k0 += 32) {
    async16(Ag0 + k0, As0);
    async16(Ag1 + k0, As1);
    async16(Bg0 + k0, Bs0);
    async16(Bg1 + k0, Bs1);
    __syncthreads();
    bf16x8 af[4], bg[4];
#pragma unroll
    for (int mi = 0; mi < 4; ++mi) {
      int row = wm * 64 + mi * 16 + l16;
      int byte = (row * 64 + lh * 16) ^ ((row & 3) << 4);
      af[mi] = *(const bf16x8*)((const char*)As + byte);
    }
#pragma unroll
    for (int ni = 0; ni < 4; ++ni) {
      int row = wn * 64 + ni * 16 + l16;
      int byte = (row * 64 + lh * 16) ^ ((row & 3) << 4);
      bg[ni] = *(const bf16x8*)((const char*)Bs + byte);
    }
#pragma unroll
    for (int mi = 0; mi < 4; ++mi)
#pragma unroll
      for (int ni = 0; ni < 4; ++ni)
        acc[mi][ni] = __builtin_amdgcn_mfma_f32_16x16x32_bf16(af[mi], bg[ni], acc[mi][ni], 0, 0, 0);
    __syncthreads();
  }

#pragma unroll
  for (int mi = 0; mi < 4; ++mi) {
    size_t row = m0 + wm * 64 + mi * 16 + lh * 4;
#pragma unroll
    for (int ni = 0; ni < 4; ++ni) {
      size_t col = n0 + wn * 64 + ni * 16 + l16;
#pragma unroll
      for (int j = 0; j < 4; ++j)
        C[(row + j) * N + col] = (OutT)acc[mi][ni][j];
    }
  }
}

// ---------------- RoPE + scatter (Q,K only; V handled by k_vtrans) -------
// QKV rows: token-major [4096][6144]. slots: 0..31 Q, 32..39 K.
__global__ void k_rope(const bf16* __restrict__ QKV, bf16* __restrict__ Qr,
                       bf16* __restrict__ Kr) {
  int gid = blockIdx.x * 256 + threadIdx.x;
  int p = gid & 63;
  int rest = gid >> 6;
  int slot = rest % 40;
  int tok = rest / 40;
  int s = tok & 2047;
  int b = tok >> 11;
  const bf16* src = QKV + (size_t)tok * 6144 + slot * 128;
  float x1 = (float)src[p], x2 = (float)src[p + 64];
  float f = exp2f((float)p * (-13.287712379549449f / 64.0f));
  float ang = (float)s * f;
  float sn, cn;
  sincosf(ang, &sn, &cn);
  float o1 = x1 * cn - x2 * sn;
  float o2 = x2 * cn + x1 * sn;
  bf16* dst;
  if (slot < 32) {
    o1 *= 0.08838834764831845f;  // fold 1/sqrt(128) into Q
    o2 *= 0.08838834764831845f;
    dst = Qr + (((size_t)b * 32 + slot) * 2048 + s) * 128;
  } else {
    dst = Kr + (((size_t)b * 8 + (slot - 32)) * 2048 + s) * 128;
  }
  dst[p] = (bf16)o1;
  dst[p + 64] = (bf16)o2;
}

// ---------------- V transpose: QKV[tok][5120+hkv*128+d] -> Vtg[b][hkv][d][s]
__global__ void k_vtrans(const bf16* __restrict__ QKV, bf16* __restrict__ Vtg) {
  __shared__ __align__(16) bf16 T[64 * 64];
  const int tid = threadIdx.x;
  const int dt = blockIdx.x & 1;
  const int st = (blockIdx.x >> 1) & 31;
  const int hh = blockIdx.x >> 6;
  const int hkv = hh & 7, b = hh >> 3;
  const int s0 = st * 64, d0 = dt * 64;
  const bf16* src = QKV + (size_t)(b * 2048 + s0) * 6144 + 5120 + hkv * 128 + d0;
#pragma unroll
  for (int k = 0; k < 2; ++k) {
    int cc = tid * 2 + k;
    int r = cc >> 3, c8 = cc & 7;
    bf16x8 v = *(const bf16x8*)(src + (size_t)r * 6144 + c8 * 8);
    int byte = (r * 128 + c8 * 16) ^ ((r & 7) << 4);
    *(bf16x8*)((char*)T + byte) = v;
  }
  __syncthreads();
  bf16* dst = Vtg + ((size_t)(b * 8 + hkv) * 128 + d0) * 2048 + s0;
#pragma unroll
  for (int k = 0; k < 2; ++k) {
    int cc = tid * 2 + k;
    int d = cc >> 3, s8 = cc & 7;
    bf16x8 v;
#pragma unroll
    for (int j = 0; j < 8; ++j) {
      int s = s8 * 8 + j;
      int byte = (s * 128 + d * 2) ^ ((s & 7) << 4);
      v[j] = *(const bf16*)((const char*)T + byte);
    }
    *(bf16x8*)(dst + (size_t)d * 2048 + s8 * 8) = v;
  }
}

// ---------------- flash attention (causal, GQA 4:1) ----------------
// grid 512: block = (b, h, pair). Each block does q-blocks {pid, 15-pid}
// of 128 rows. 4 waves x 32 q-rows. KV tile = 64, double-buffered LDS.
// K [64][128] and Vt [128][64] XOR-swizzled (byte ^= (row&7)<<4), staged
// via global_load_lds with pre-swizzled source. P per-wave [32][64] swizzled.
__global__ __launch_bounds__(256, 2) void k_flash(
    const bf16* __restrict__ Qr, const bf16* __restrict__ Kr,
    const bf16* __restrict__ Vtg, bf16* __restrict__ Out) {
  __shared__ __align__(16) bf16 Kl[2][64 * 128];
  __shared__ __align__(16) bf16 Vl[2][128 * 64];
  __shared__ __align__(16) bf16 Pl[4][32 * 64];
  const int tid = threadIdx.x;
  const int lane = tid & 63;
  const int w = tid >> 6;
  const int l16 = lane & 15, lh = lane >> 4;
  const int pid = blockIdx.x & 7;
  const int hl = blockIdx.x >> 3;  // 0..63
  const int h = hl & 31, b = hl >> 5;
  const int hkv = h >> 2;
  const bf16* Kbase = Kr + ((size_t)(b * 8 + hkv)) * 2048 * 128;
  const bf16* Vbase = Vtg + ((size_t)(b * 8 + hkv)) * 128 * 2048;
  bf16* P = &Pl[w][0];

  // per-thread staging constants (4 chunks each for K and V per tile)
  int kOff[4], vOff[4], ldsOff[4];
#pragma unroll
  for (int i = 0; i < 4; ++i) {
    int c = (w * 4 + i) * 64 + lane;
    ldsOff[i] = c * 8;  // elements
    int r = c >> 4, p = c & 15;
    kOff[i] = r * 128 + (p ^ (r & 7)) * 8;
    int r2 = c >> 3, p2 = c & 7;
    vOff[i] = r2 * 2048 + (p2 ^ (r2 & 7)) * 8;
  }

  for (int qi = 0; qi < 2; ++qi) {
    const int q = qi ? (15 - pid) : pid;
    const int q0 = q * 128;
    const int nt = 2 * q + 2;

    bf16x8 qf[2][4];
#pragma unroll
    for (int m = 0; m < 2; ++m) {
      const bf16* qb = Qr + (((size_t)(b * 32 + h)) * 2048 + q0 + w * 32 + m * 16 + l16) * 128 + lh * 8;
#pragma unroll
      for (int kc = 0; kc < 4; ++kc) qf[m][kc] = *(const bf16x8*)(qb + kc * 32);
    }
    f32x4 acc[2][8] = {};
    float mrow[2][4] = {{-1e30f, -1e30f, -1e30f, -1e30f}, {-1e30f, -1e30f, -1e30f, -1e30f}};
    float lrow[2][4] = {};

    // prologue: stage tile 0 into buf 0
#pragma unroll
    for (int i = 0; i < 4; ++i) {
      async16(Kbase + kOff[i], &Kl[0][0] + ldsOff[i]);
      async16(Vbase + vOff[i], &Vl[0][0] + ldsOff[i]);
    }
    __syncthreads();

    for (int t = 0; t < nt; ++t) {
      const int cur = t & 1;
      if (t + 1 < nt) {
        const int nb = t + 1;
#pragma unroll
        for (int i = 0; i < 4; ++i) {
          async16(Kbase + (size_t)nb * 8192 + kOff[i], &Kl[cur ^ 1][0] + ldsOff[i]);
          async16(Vbase + (size_t)nb * 64 + vOff[i], &Vl[cur ^ 1][0] + ldsOff[i]);
        }
      }
      // S = Q K^T
      f32x4 sf[2][4] = {};
#pragma unroll
      for (int ni = 0; ni < 4; ++ni) {
        int row = ni * 16 + l16;
        bf16x8 kf[4];
#pragma unroll
        for (int kc = 0; kc < 4; ++kc) {
          int byte = (row * 256 + kc * 64 + lh * 16) ^ ((row & 7) << 4);
          kf[kc] = *(const bf16x8*)((const char*)&Kl[cur][0] + byte);
        }
#pragma unroll
        for (int m = 0; m < 2; ++m)
#pragma unroll
          for (int kc = 0; kc < 4; ++kc)
            sf[m][ni] = __builtin_amdgcn_mfma_f32_16x16x32_bf16(qf[m][kc], kf[kc], sf[m][ni], 0, 0, 0);
      }
      // causal mask on diagonal tiles
      if (t >= 2 * q) {
#pragma unroll
        for (int m = 0; m < 2; ++m)
#pragma unroll
          for (int ni = 0; ni < 4; ++ni) {
            int key = t * 64 + ni * 16 + l16;
#pragma unroll
            for (int j = 0; j < 4; ++j) {
              int rowg = q0 + w * 32 + m * 16 + lh * 4 + j;
              if (key > rowg) sf[m][ni][j] = -1e30f;
            }
          }
      }
      // online softmax
      float corr[2][4];
#pragma unroll
      for (int m = 0; m < 2; ++m)
#pragma unroll
        for (int j = 0; j < 4; ++j) {
          float mx = fmaxf(fmaxf(sf[m][0][j], sf[m][1][j]), fmaxf(sf[m][2][j], sf[m][3][j]));
          mx = fmaxf(mx, __shfl_xor(mx, 1));
          mx = fmaxf(mx, __shfl_xor(mx, 2));
          mx = fmaxf(mx, __shfl_xor(mx, 4));
          mx = fmaxf(mx, __shfl_xor(mx, 8));
          float mn = fmaxf(mrow[m][j], mx);
          corr[m][j] = __expf(mrow[m][j] - mn);
          mrow[m][j] = mn;
          float rs = 0.f;
#pragma unroll
          for (int ni = 0; ni < 4; ++ni) {
            float pv = __expf(sf[m][ni][j] - mn);
            sf[m][ni][j] = pv;
            rs += pv;
          }
          rs += __shfl_xor(rs, 1);
          rs += __shfl_xor(rs, 2);
          rs += __shfl_xor(rs, 4);
          rs += __shfl_xor(rs, 8);
          lrow[m][j] = lrow[m][j] * corr[m][j] + rs;
        }
#pragma unroll
      for (int m = 0; m < 2; ++m)
#pragma unroll
        for (int di = 0; di < 8; ++di)
#pragma unroll
          for (int j = 0; j < 4; ++j) acc[m][di][j] *= corr[m][j];
      // P -> per-wave LDS (swizzled)
#pragma unroll
      for (int m = 0; m < 2; ++m)
#pragma unroll
        for (int ni = 0; ni < 4; ++ni)
#pragma unroll
          for (int j = 0; j < 4; ++j) {
            int row = m * 16 + lh * 4 + j;
            int byte = (row * 128 + ni * 32 + l16 * 2) ^ ((row & 7) << 4);
            *(bf16*)((char*)P + byte) = (bf16)sf[m][ni][j];
          }
      // O += P @ V
#pragma unroll
      for (int kc = 0; kc < 2; ++kc) {
        bf16x8 pa[2];
#pragma unroll
        for (int m = 0; m < 2; ++m) {
          int row = m * 16 + l16;
          int byte = (row * 128 + kc * 64 + lh * 16) ^ ((row & 7) << 4);
          pa[m] = *(const bf16x8*)((const char*)P + byte);
        }
#pragma unroll
        for (int di = 0; di < 8; ++di) {
          int d = di * 16 + l16;
          int byte = (d * 128 + kc * 64 + lh * 16) ^ ((d & 7) << 4);
          bf16x8 vb = *(const bf16x8*)((const char*)&Vl[cur][0] + byte);
#pragma unroll
          for (int m = 0; m < 2; ++m)
            acc[m][di] = __builtin_amdgcn_mfma_f32_16x16x32_bf16(pa[m], vb, acc[m][di], 0, 0, 0);
        }
      }
      __syncthreads();
    }

    // epilogue
#pragma unroll
    for (int m = 0; m < 2; ++m)
#pragma unroll
      for (int j = 0; j < 4; ++j) {
        float inv = 1.0f / lrow[m][j];
        int rowg = q0 + w * 32 + m * 16 + lh * 4 + j;
        bf16* ob = Out + ((size_t)(b * 2048) + rowg) * 4096 + h * 128 + l16;
#pragma unroll
        for (int di = 0; di < 8; ++di)
          ob[di * 16] = (bf16)(acc[m][di][j] * inv);
      }
  }
}

// ---------------- launch ----------------
extern "C" void kernel_launch(void* const* d_in, const int* in_sizes, int n_in,
                              void* d_out, int out_size, void* d_ws, size_t ws_size,
                              hipStream_t stream) {
  const float* hidden = (const float*)d_in[0];
  const float* Wq = (const float*)d_in[3];
  const float* Wk = (const float*)d_in[4];
  const float* Wv = (const float*)d_in[5];
  const float* Wo = (const float*)d_in[6];
  float* out = (float*)d_out;

  // workspace layout (bytes):
  //   Xb   [4096*4096] bf16 @ 0        (reused as AttnOut)
  //   Wqkv [6144*4096] bf16 @ 32M      (reused as Wo_bf16)
  //   QKV  [4096*6144] bf16 @ 80M
  //   Qr   [2,32,2048,128] bf16 @ 128M
  //   Kr   [2,8,2048,128]  bf16 @ 160M
  //   Vtg  [2,8,128,2048]  bf16 @ 168M   total 176 MiB
  char* ws = (char*)d_ws;
  if (ws_size < 184549376u) return;
  bf16* Xb = (bf16*)(ws);
  bf16* Wqkv = (bf16*)(ws + 33554432u);
  bf16* QKV = (bf16*)(ws + 83886080u);
  bf16* Qr = (bf16*)(ws + 134217728u);
  bf16* Kr = (bf16*)(ws + 167772160u);
  bf16* Vtg = (bf16*)(ws + 176160768u);
  bf16* AttnO = Xb;
  bf16* Wob = Wqkv;

  k_cvt<<<8192, 256, 0, stream>>>(hidden, Xb, 2097152);
  k_cvt<<<8192, 256, 0, stream>>>(Wq, Wqkv, 2097152);
  k_cvt<<<2048, 256, 0, stream>>>(Wk, Wqkv + 16777216u, 524288);
  k_cvt<<<2048, 256, 0, stream>>>(Wv, Wqkv + 20971520u, 524288);
  k_gemm_bt<bf16><<<dim3(48, 32), 256, 0, stream>>>(Xb, Wqkv, QKV, 4096, 6144, 4096);
  k_rope<<<40960, 256, 0, stream>>>(QKV, Qr, Kr);
  k_vtrans<<<1024, 256, 0, stream>>>(QKV, Vtg);
  k_cvt<<<8192, 256, 0, stream>>>(Wo, Wob, 2097152);
  k_flash<<<512, 256, 0, stream>>>(Qr, Kr, Vtg, AttnO);
  k_gemm_bt<float><<<dim3(32, 32), 256, 0, stream>>>(AttnO, Wob, out, 4096, 4096, 4096);
}

// Round 3
// 615.588 us; speedup vs baseline: 1.4357x; 1.1739x over previous
//
#include <hip/hip_runtime.h>
#include <hip/hip_bf16.h>

// Llama attention block: B=2, S=2048, H=4096, NH=32, NKV=8, HD=128, GQA 4:1.
// Pipeline (bf16 MFMA, fp32 accumulate):
//   1. convert hidden + Wq/Wk/Wv (concat) + Wo to bf16
//   2. QKV = X @ Wqkv^T   (M=4096,N=6144,K=4096)  256^2 8-phase MFMA GEMM
//   3. RoPE (Q,K) + scatter; fold 1/sqrt(128) into Q
//   4. V transpose: QKV -> Vtg [b][hkv][128 d][2048 s]
//   5. flash attention (causal), QBLK=128, KV tile 64, dbuf LDS, paired blocks
//   6. out = AttnOut @ Wo^T  (fp32 out), same 8-phase GEMM

typedef __bf16 bf16;
typedef __bf16 bf16x8 __attribute__((ext_vector_type(8)));
typedef float f32x4 __attribute__((ext_vector_type(4)));

#define UNROLL _Pragma("unroll")

__device__ __forceinline__ void async16(const bf16* g, bf16* l) {
  __builtin_amdgcn_global_load_lds(
      (const __attribute__((address_space(1))) void*)g,
      (__attribute__((address_space(3))) void*)l,
      16, 0, 0);
}

// ---------------- fp32 -> bf16 convert (8 elem/thread) ----------------
__global__ void k_cvt(const float* __restrict__ s, bf16* __restrict__ d, int n8) {
  int i = blockIdx.x * 256 + threadIdx.x;
  if (i >= n8) return;
  const float4* sp = (const float4*)s + (size_t)i * 2;
  float4 a = sp[0], b = sp[1];
  bf16x8 o = { (bf16)a.x, (bf16)a.y, (bf16)a.z, (bf16)a.w,
               (bf16)b.x, (bf16)b.y, (bf16)b.z, (bf16)b.w };
  *(bf16x8*)(d + (size_t)i * 8) = o;
}

// ---------------- 256^2 8-phase GEMM: C[M,N] = A[M,K] * Bw[N,K]^T --------
// 8 waves (2M x 4N), BK=64, LDS = 2 dbuf x 4 units (Ak0,Ak1,Bk0,Bk1) of
// [256 rows][32 cols] bf16 (16 KiB each) = 128 KiB. Swizzle: within a unit,
// byte p -> p ^ (((p>>7)&3)<<4)  (XOR 16B-slot with row>>1; involution).
// Stage via global_load_lds (linear dest, inverse-swizzled global source).
// Counted vmcnt(4): loads for tile t+1 issued one phase each; never drained.
#define BARR { __builtin_amdgcn_s_barrier(); __builtin_amdgcn_sched_barrier(0); }
#define VMCNT4 { asm volatile("s_waitcnt vmcnt(4)" ::: "memory"); __builtin_amdgcn_sched_barrier(0); }
#define VMCNT0 { asm volatile("s_waitcnt vmcnt(0)" ::: "memory"); __builtin_amdgcn_sched_barrier(0); }

template <typename OutT>
__global__ __launch_bounds__(512, 2) void k_gemm8(
    const bf16* __restrict__ A, const bf16* __restrict__ Bw,
    OutT* __restrict__ C, int M, int N, int K, int nxt) {
  __shared__ __align__(16) bf16 lds[2][4][256 * 32];  // 128 KiB
  const int tid = threadIdx.x;
  const int lane = tid & 63;
  const int w = tid >> 6;             // 0..7
  const int wm = w >> 2, wn = w & 3;  // 2M x 4N
  const int l16 = lane & 15, lh = lane >> 4;

  // XCD-aware bijective block swizzle (grid % 8 == 0 for all our grids)
  const int nwg = gridDim.x;
  const int cpx = nwg >> 3;
  const int bid = blockIdx.x;
  const int swz = (bid & 7) * cpx + (bid >> 3);
  const int by = swz / nxt, bx = swz % nxt;
  const size_t m0 = (size_t)by * 256, n0 = (size_t)bx * 256;

  // staging: per thread 2 chunks of 16B per half-unit; dest linear, source
  // inverse-swizzled (same involution)
  int rr[2], ce[2], dOff[2];
  UNROLL for (int i = 0; i < 2; ++i) {
    int d = (w * 2 + i) * 1024 + lane * 16;
    rr[i] = d >> 6;                                    // row 0..255
    ce[i] = ((d & 63) ^ (((d >> 7) & 3) << 4)) >> 1;   // col elem 0..31
    dOff[i] = (w * 2 + i) * 512 + lane * 8;            // elements
  }
  const bf16* gA[2];
  const bf16* gB[2];
  UNROLL for (int i = 0; i < 2; ++i) {
    gA[i] = A + (m0 + rr[i]) * K + ce[i];
    gB[i] = Bw + (n0 + rr[i]) * K + ce[i];
  }

#define STAGE_A(bufi, ks, kk)                                          \
  { async16(gA[0] + (kk) + (ks) * 32, &lds[bufi][ks][0] + dOff[0]);    \
    async16(gA[1] + (kk) + (ks) * 32, &lds[bufi][ks][0] + dOff[1]); }
#define STAGE_B(bufi, ks, kk)                                          \
  { async16(gB[0] + (kk) + (ks) * 32, &lds[bufi][2 + (ks)][0] + dOff[0]); \
    async16(gB[1] + (kk) + (ks) * 32, &lds[bufi][2 + (ks)][0] + dOff[1]); }

  auto rd = [&](const bf16* unitBase, int row) -> bf16x8 {
    int p = row * 64 + lh * 16;
    p ^= ((p >> 7) & 3) << 4;
    return *(const bf16x8*)((const char*)unitBase + p);
  };

#define PHASE_READS(cur, mh, ks)                                           \
  UNROLL for (int x = 0; x < 4; ++x)                                       \
    Ar[x] = rd(&lds[cur][ks][0], wm * 128 + (mh) * 64 + x * 16 + l16);     \
  UNROLL for (int y = 0; y < 4; ++y)                                       \
    Br[y] = rd(&lds[cur][2 + (ks)][0], wn * 64 + y * 16 + l16);

#define PHASE_MFMA(mh)                                                     \
  { asm volatile("s_waitcnt lgkmcnt(0)" ::: "memory");                     \
    __builtin_amdgcn_sched_barrier(0);                                     \
    __builtin_amdgcn_s_setprio(1);                                         \
    UNROLL for (int x = 0; x < 4; ++x)                                     \
      UNROLL for (int y = 0; y < 4; ++y)                                   \
        acc[(mh) * 4 + x][y] = __builtin_amdgcn_mfma_f32_16x16x32_bf16(    \
            Ar[x], Br[y], acc[(mh) * 4 + x][y], 0, 0, 0);                  \
    __builtin_amdgcn_s_setprio(0); }

  f32x4 acc[8][4] = {};
  const int NT = K >> 6;

  // prologue: stage tile 0 (order Ak0,Bk0,Ak1,Bk1)
  STAGE_A(0, 0, 0); STAGE_B(0, 0, 0); STAGE_A(0, 1, 0); STAGE_B(0, 1, 0);
  VMCNT4;  // Ak0,Bk0 landed
  BARR;

  for (int t = 0; t < NT - 1; ++t) {
    const int cur = t & 1, nb = cur ^ 1;
    const int kk = (t + 1) << 6;
    bf16x8 Ar[4], Br[4];
    // p1: quadrant (mh0, k0); stage next Ak0
    PHASE_READS(cur, 0, 0);
    STAGE_A(nb, 0, kk);
    BARR; PHASE_MFMA(0); BARR;
    // p2: (mh1, k0); stage next Bk0; wait: tile t's Ak1,Bk1 landed
    PHASE_READS(cur, 1, 0);
    STAGE_B(nb, 0, kk);
    VMCNT4;
    BARR; PHASE_MFMA(1); BARR;
    // p3: (mh0, k1); stage next Ak1
    PHASE_READS(cur, 0, 1);
    STAGE_A(nb, 1, kk);
    BARR; PHASE_MFMA(0); BARR;
    // p4: (mh1, k1); stage next Bk1; wait: tile t+1's Ak0,Bk0 landed
    PHASE_READS(cur, 1, 1);
    STAGE_B(nb, 1, kk);
    VMCNT4;
    BARR; PHASE_MFMA(1); BARR;
  }
  // epilogue tile (no staging)
  {
    const int cur = (NT - 1) & 1;
    bf16x8 Ar[4], Br[4];
    PHASE_READS(cur, 0, 0);
    BARR; PHASE_MFMA(0); BARR;
    PHASE_READS(cur, 1, 0);
    VMCNT0;  // remaining Ak1,Bk1
    BARR; PHASE_MFMA(1); BARR;
    PHASE_READS(cur, 0, 1);
    BARR; PHASE_MFMA(0); BARR;
    PHASE_READS(cur, 1, 1);
    BARR; PHASE_MFMA(1);
  }

  // C write: row = m0 + wm*128 + mi*16 + lh*4 + j ; col = n0 + wn*64 + ni*16 + l16
  UNROLL for (int mi = 0; mi < 8; ++mi) {
    size_t row = m0 + wm * 128 + mi * 16 + lh * 4;
    UNROLL for (int ni = 0; ni < 4; ++ni) {
      size_t col = n0 + wn * 64 + ni * 16 + l16;
      UNROLL for (int j = 0; j < 4; ++j)
        C[(row + j) * N + col] = (OutT)acc[mi][ni][j];
    }
  }
#undef STAGE_A
#undef STAGE_B
#undef PHASE_READS
#undef PHASE_MFMA
}

// ---------------- RoPE + scatter (Q,K only; V handled by k_vtrans) -------
__global__ void k_rope(const bf16* __restrict__ QKV, bf16* __restrict__ Qr,
                       bf16* __restrict__ Kr) {
  int gid = blockIdx.x * 256 + threadIdx.x;
  int p = gid & 63;
  int rest = gid >> 6;
  int slot = rest % 40;
  int tok = rest / 40;
  int s = tok & 2047;
  int b = tok >> 11;
  const bf16* src = QKV + (size_t)tok * 6144 + slot * 128;
  float x1 = (float)src[p], x2 = (float)src[p + 64];
  float f = exp2f((float)p * (-13.287712379549449f / 64.0f));
  float ang = (float)s * f;
  float sn, cn;
  sincosf(ang, &sn, &cn);
  float o1 = x1 * cn - x2 * sn;
  float o2 = x2 * cn + x1 * sn;
  bf16* dst;
  if (slot < 32) {
    o1 *= 0.08838834764831845f;  // fold 1/sqrt(128) into Q
    o2 *= 0.08838834764831845f;
    dst = Qr + (((size_t)b * 32 + slot) * 2048 + s) * 128;
  } else {
    dst = Kr + (((size_t)b * 8 + (slot - 32)) * 2048 + s) * 128;
  }
  dst[p] = (bf16)o1;
  dst[p + 64] = (bf16)o2;
}

// ---------------- V transpose: QKV[tok][5120+hkv*128+d] -> Vtg[b][hkv][d][s]
__global__ void k_vtrans(const bf16* __restrict__ QKV, bf16* __restrict__ Vtg) {
  __shared__ __align__(16) bf16 T[64 * 64];
  const int tid = threadIdx.x;
  const int dt = blockIdx.x & 1;
  const int st = (blockIdx.x >> 1) & 31;
  const int hh = blockIdx.x >> 6;
  const int hkv = hh & 7, b = hh >> 3;
  const int s0 = st * 64, d0 = dt * 64;
  const bf16* src = QKV + (size_t)(b * 2048 + s0) * 6144 + 5120 + hkv * 128 + d0;
  UNROLL for (int k = 0; k < 2; ++k) {
    int cc = tid * 2 + k;
    int r = cc >> 3, c8 = cc & 7;
    bf16x8 v = *(const bf16x8*)(src + (size_t)r * 6144 + c8 * 8);
    int byte = (r * 128 + c8 * 16) ^ ((r & 7) << 4);
    *(bf16x8*)((char*)T + byte) = v;
  }
  __syncthreads();
  bf16* dst = Vtg + ((size_t)(b * 8 + hkv) * 128 + d0) * 2048 + s0;
  UNROLL for (int k = 0; k < 2; ++k) {
    int cc = tid * 2 + k;
    int d = cc >> 3, s8 = cc & 7;
    bf16x8 v;
    UNROLL for (int j = 0; j < 8; ++j) {
      int s = s8 * 8 + j;
      int byte = (s * 128 + d * 2) ^ ((s & 7) << 4);
      v[j] = *(const bf16*)((const char*)T + byte);
    }
    *(bf16x8*)(dst + (size_t)d * 2048 + s8 * 8) = v;
  }
}

// ---------------- flash attention (causal, GQA 4:1) ----------------
__global__ __launch_bounds__(256, 2) void k_flash(
    const bf16* __restrict__ Qr, const bf16* __restrict__ Kr,
    const bf16* __restrict__ Vtg, bf16* __restrict__ Out) {
  __shared__ __align__(16) bf16 Kl[2][64 * 128];
  __shared__ __align__(16) bf16 Vl[2][128 * 64];
  __shared__ __align__(16) bf16 Pl[4][32 * 64];
  const int tid = threadIdx.x;
  const int lane = tid & 63;
  const int w = tid >> 6;
  const int l16 = lane & 15, lh = lane >> 4;
  const int pid = blockIdx.x & 7;
  const int hl = blockIdx.x >> 3;
  const int h = hl & 31, b = hl >> 5;
  const int hkv = h >> 2;
  const bf16* Kbase = Kr + ((size_t)(b * 8 + hkv)) * 2048 * 128;
  const bf16* Vbase = Vtg + ((size_t)(b * 8 + hkv)) * 128 * 2048;
  bf16* P = &Pl[w][0];

  int kOff[4], vOff[4], ldsOff[4];
  UNROLL for (int i = 0; i < 4; ++i) {
    int c = (w * 4 + i) * 64 + lane;
    ldsOff[i] = c * 8;
    int r = c >> 4, p = c & 15;
    kOff[i] = r * 128 + (p ^ (r & 7)) * 8;
    int r2 = c >> 3, p2 = c & 7;
    vOff[i] = r2 * 2048 + (p2 ^ (r2 & 7)) * 8;
  }

  for (int qi = 0; qi < 2; ++qi) {
    const int q = qi ? (15 - pid) : pid;
    const int q0 = q * 128;
    const int nt = 2 * q + 2;

    bf16x8 qf[2][4];
    UNROLL for (int m = 0; m < 2; ++m) {
      const bf16* qb = Qr + (((size_t)(b * 32 + h)) * 2048 + q0 + w * 32 + m * 16 + l16) * 128 + lh * 8;
      UNROLL for (int kc = 0; kc < 4; ++kc) qf[m][kc] = *(const bf16x8*)(qb + kc * 32);
    }
    f32x4 acc[2][8] = {};
    float mrow[2][4] = {{-1e30f, -1e30f, -1e30f, -1e30f}, {-1e30f, -1e30f, -1e30f, -1e30f}};
    float lrow[2][4] = {};

    UNROLL for (int i = 0; i < 4; ++i) {
      async16(Kbase + kOff[i], &Kl[0][0] + ldsOff[i]);
      async16(Vbase + vOff[i], &Vl[0][0] + ldsOff[i]);
    }
    __syncthreads();

    for (int t = 0; t < nt; ++t) {
      const int cur = t & 1;
      if (t + 1 < nt) {
        const int nb = t + 1;
        UNROLL for (int i = 0; i < 4; ++i) {
          async16(Kbase + (size_t)nb * 8192 + kOff[i], &Kl[cur ^ 1][0] + ldsOff[i]);
          async16(Vbase + (size_t)nb * 64 + vOff[i], &Vl[cur ^ 1][0] + ldsOff[i]);
        }
      }
      f32x4 sf[2][4] = {};
      UNROLL for (int ni = 0; ni < 4; ++ni) {
        int row = ni * 16 + l16;
        bf16x8 kf[4];
        UNROLL for (int kc = 0; kc < 4; ++kc) {
          int byte = (row * 256 + kc * 64 + lh * 16) ^ ((row & 7) << 4);
          kf[kc] = *(const bf16x8*)((const char*)&Kl[cur][0] + byte);
        }
        UNROLL for (int m = 0; m < 2; ++m)
          UNROLL for (int kc = 0; kc < 4; ++kc)
            sf[m][ni] = __builtin_amdgcn_mfma_f32_16x16x32_bf16(qf[m][kc], kf[kc], sf[m][ni], 0, 0, 0);
      }
      if (t >= 2 * q) {
        UNROLL for (int m = 0; m < 2; ++m)
          UNROLL for (int ni = 0; ni < 4; ++ni) {
            int key = t * 64 + ni * 16 + l16;
            UNROLL for (int j = 0; j < 4; ++j) {
              int rowg = q0 + w * 32 + m * 16 + lh * 4 + j;
              if (key > rowg) sf[m][ni][j] = -1e30f;
            }
          }
      }
      float corr[2][4];
      UNROLL for (int m = 0; m < 2; ++m)
        UNROLL for (int j = 0; j < 4; ++j) {
          float mx = fmaxf(fmaxf(sf[m][0][j], sf[m][1][j]), fmaxf(sf[m][2][j], sf[m][3][j]));
          mx = fmaxf(mx, __shfl_xor(mx, 1));
          mx = fmaxf(mx, __shfl_xor(mx, 2));
          mx = fmaxf(mx, __shfl_xor(mx, 4));
          mx = fmaxf(mx, __shfl_xor(mx, 8));
          float mn = fmaxf(mrow[m][j], mx);
          corr[m][j] = __expf(mrow[m][j] - mn);
          mrow[m][j] = mn;
          float rs = 0.f;
          UNROLL for (int ni = 0; ni < 4; ++ni) {
            float pv = __expf(sf[m][ni][j] - mn);
            sf[m][ni][j] = pv;
            rs += pv;
          }
          rs += __shfl_xor(rs, 1);
          rs += __shfl_xor(rs, 2);
          rs += __shfl_xor(rs, 4);
          rs += __shfl_xor(rs, 8);
          lrow[m][j] = lrow[m][j] * corr[m][j] + rs;
        }
      UNROLL for (int m = 0; m < 2; ++m)
        UNROLL for (int di = 0; di < 8; ++di)
          UNROLL for (int j = 0; j < 4; ++j) acc[m][di][j] *= corr[m][j];
      UNROLL for (int m = 0; m < 2; ++m)
        UNROLL for (int ni = 0; ni < 4; ++ni)
          UNROLL for (int j = 0; j < 4; ++j) {
            int row = m * 16 + lh * 4 + j;
            int byte = (row * 128 + ni * 32 + l16 * 2) ^ ((row & 7) << 4);
            *(bf16*)((char*)P + byte) = (bf16)sf[m][ni][j];
          }
      UNROLL for (int kc = 0; kc < 2; ++kc) {
        bf16x8 pa[2];
        UNROLL for (int m = 0; m < 2; ++m) {
          int row = m * 16 + l16;
          int byte = (row * 128 + kc * 64 + lh * 16) ^ ((row & 7) << 4);
          pa[m] = *(const bf16x8*)((const char*)P + byte);
        }
        UNROLL for (int di = 0; di < 8; ++di) {
          int d = di * 16 + l16;
          int byte = (d * 128 + kc * 64 + lh * 16) ^ ((d & 7) << 4);
          bf16x8 vb = *(const bf16x8*)((const char*)&Vl[cur][0] + byte);
          UNROLL for (int m = 0; m < 2; ++m)
            acc[m][di] = __builtin_amdgcn_mfma_f32_16x16x32_bf16(pa[m], vb, acc[m][di], 0, 0, 0);
        }
      }
      __syncthreads();
    }

    UNROLL for (int m = 0; m < 2; ++m)
      UNROLL for (int j = 0; j < 4; ++j) {
        float inv = 1.0f / lrow[m][j];
        int rowg = q0 + w * 32 + m * 16 + lh * 4 + j;
        bf16* ob = Out + ((size_t)(b * 2048) + rowg) * 4096 + h * 128 + l16;
        UNROLL for (int di = 0; di < 8; ++di)
          ob[di * 16] = (bf16)(acc[m][di][j] * inv);
      }
  }
}

// ---------------- launch ----------------
extern "C" void kernel_launch(void* const* d_in, const int* in_sizes, int n_in,
                              void* d_out, int out_size, void* d_ws, size_t ws_size,
                              hipStream_t stream) {
  const float* hidden = (const float*)d_in[0];
  const float* Wq = (const float*)d_in[3];
  const float* Wk = (const float*)d_in[4];
  const float* Wv = (const float*)d_in[5];
  const float* Wo = (const float*)d_in[6];
  float* out = (float*)d_out;

  char* ws = (char*)d_ws;
  if (ws_size < 184549376u) return;
  bf16* Xb = (bf16*)(ws);
  bf16* Wqkv = (bf16*)(ws + 33554432u);
  bf16* QKV = (bf16*)(ws + 83886080u);
  bf16* Qr = (bf16*)(ws + 134217728u);
  bf16* Kr = (bf16*)(ws + 167772160u);
  bf16* Vtg = (bf16*)(ws + 176160768u);
  bf16* AttnO = Xb;
  bf16* Wob = Wqkv;

  k_cvt<<<8192, 256, 0, stream>>>(hidden, Xb, 2097152);
  k_cvt<<<8192, 256, 0, stream>>>(Wq, Wqkv, 2097152);
  k_cvt<<<2048, 256, 0, stream>>>(Wk, Wqkv + 16777216u, 524288);
  k_cvt<<<2048, 256, 0, stream>>>(Wv, Wqkv + 20971520u, 524288);
  // QKV GEMM: M=4096,N=6144 -> 16 x 24 = 384 blocks (384 % 8 == 0)
  k_gemm8<bf16><<<384, 512, 0, stream>>>(Xb, Wqkv, QKV, 4096, 6144, 4096, 24);
  k_rope<<<40960, 256, 0, stream>>>(QKV, Qr, Kr);
  k_vtrans<<<1024, 256, 0, stream>>>(QKV, Vtg);
  k_cvt<<<8192, 256, 0, stream>>>(Wo, Wob, 2097152);
  k_flash<<<512, 256, 0, stream>>>(Qr, Kr, Vtg, AttnO);
  // O-proj: M=N=4096 -> 16 x 16 = 256 blocks
  k_gemm8<float><<<256, 512, 0, stream>>>(AttnO, Wob, out, 4096, 4096, 4096, 16);
}